// Round 6
// baseline (191.167 us; speedup 1.0000x reference)
//
#include <hip/hip_runtime.h>

// Problem constants
#define BATCH 16384
#define KEYD  64
#define DDIM  128
#define UDIM  128
#define MODES 32

typedef __attribute__((ext_vector_type(8))) short bf16x8;   // 8 bf16 in 4 VGPRs
typedef __attribute__((ext_vector_type(4))) float f32x4;

__device__ __forceinline__ unsigned short f2bf(float f) {
  unsigned u = __float_as_uint(f);
  unsigned r = (u + 0x7FFFu + ((u >> 16) & 1u)) >> 16;  // RNE bf16
  return (unsigned short)r;
}

__device__ __forceinline__ void gld_lds16(const void* g, void* l) {
  __builtin_amdgcn_global_load_lds(
      (const __attribute__((address_space(1))) unsigned int*)g,
      (__attribute__((address_space(3))) unsigned int*)l, 16, 0, 0);
}

// ---------------------------------------------------------------------------
// Prep (one dispatch):
//  blocks [0,512):    sim softmax, 32 rows/block (x cast removed — the gemm
//                     now loads x fp32 directly).
//  blocks [512,770):  cast kernels+biases to bf16, MFMA-B fragment layout
//                     kb16[m][kblk][u][j] = kernels[m][kblk*8+j][u].
//  block  770:        zero the 128 row-tile counters (ws is poisoned 0xAA).
// ---------------------------------------------------------------------------
__global__ __launch_bounds__(256) void prep_all(
    const float* __restrict__ key, const float* __restrict__ sens,
    const float* __restrict__ keys_map, const float* __restrict__ kernels,
    const float* __restrict__ biases, float* __restrict__ sim,
    unsigned short* __restrict__ kb16, unsigned short* __restrict__ bb16,
    int* __restrict__ cnt) {
  const int t = threadIdx.x;
  const int bid = blockIdx.x;

  if (bid < BATCH / 32) {
    __shared__ float kr[32][KEYD];  // 32 key rows, 8KB
    *(float4*)(&kr[0][0] + t * 4) =
        *(const float4*)(key + (long)bid * 32 * KEYD + t * 4);
    *(float4*)(&kr[0][0] + 1024 + t * 4) =
        *(const float4*)(key + (long)bid * 32 * KEYD + 1024 + t * 4);

    const int lane = t & 63, wave = t >> 6;
    const int m = lane & 31, h = lane >> 5;
    float kreg[32];  // this lane's half of mode m's key row
    {
      const float* kmp = keys_map + m * KEYD + h * 32;
      #pragma unroll
      for (int j = 0; j < 32; j += 4) {
        const float4 v = *(const float4*)(kmp + j);
        kreg[j] = v.x; kreg[j + 1] = v.y; kreg[j + 2] = v.z; kreg[j + 3] = v.w;
      }
    }
    const float sv = sens[m];
    __syncthreads();

    #pragma unroll
    for (int rr = 0; rr < 8; ++rr) {
      const int rl = wave * 8 + rr;
      const long row = (long)bid * 32 + rl;

      float d2h = 0.f;
      #pragma unroll
      for (int j = 0; j < 32; j += 2) {
        const float2 kv = *(const float2*)(&kr[rl][h * 32 + j]);
        float a = kv.x - kreg[j], b = kv.y - kreg[j + 1];
        d2h += a * a + b * b;
      }
      float d2 = d2h + __shfl_xor(d2h, 32, 64);
      float logit = sv / (sqrtf(d2) + 1.0f);
      float mx = logit;
      #pragma unroll
      for (int off = 16; off > 0; off >>= 1) mx = fmaxf(mx, __shfl_xor(mx, off, 64));
      float e = __expf(logit - mx);
      float s = e;
      #pragma unroll
      for (int off = 16; off > 0; off >>= 1) s += __shfl_xor(s, off, 64);
      if (h == 0) sim[row * MODES + m] = e / s;
    }
  } else if (bid < BATCH / 32 + 258) {
    int tt = (bid - BATCH / 32) * 256 + t;
    if (tt < MODES * 16 * UDIM) {  // 65536 chunks of 8
      int u = tt & 127, kb = (tt >> 7) & 15, m = tt >> 11;
      const float* src = kernels + (long)((m * 16 + kb) * 8) * UDIM + u;
      ushort4 lo, hi;
      lo.x = f2bf(src[0 * UDIM]); lo.y = f2bf(src[1 * UDIM]);
      lo.z = f2bf(src[2 * UDIM]); lo.w = f2bf(src[3 * UDIM]);
      hi.x = f2bf(src[4 * UDIM]); hi.y = f2bf(src[5 * UDIM]);
      hi.z = f2bf(src[6 * UDIM]); hi.w = f2bf(src[7 * UDIM]);
      *(ushort4*)(kb16 + (long)tt * 8) = lo;
      *(ushort4*)(kb16 + (long)tt * 8 + 4) = hi;
    } else {  // 512 bias chunks
      int tb = tt - MODES * 16 * UDIM;
      int u = tb & 127, kb = tb >> 7;
      const float* src = biases + kb * 8 * UDIM + u;
      ushort4 lo, hi;
      lo.x = f2bf(src[0 * UDIM]); lo.y = f2bf(src[1 * UDIM]);
      lo.z = f2bf(src[2 * UDIM]); lo.w = f2bf(src[3 * UDIM]);
      hi.x = f2bf(src[4 * UDIM]); hi.y = f2bf(src[5 * UDIM]);
      hi.z = f2bf(src[6 * UDIM]); hi.w = f2bf(src[7 * UDIM]);
      *(ushort4*)(bb16 + (long)tb * 8) = lo;
      *(ushort4*)(bb16 + (long)tb * 8 + 4) = hi;
    }
  } else {
    if (t < BATCH / 128) cnt[t] = 0;  // zero row-tile counters
  }
}

// ---------------------------------------------------------------------------
// GEMM + fused reduce.  out[b,u] = (1/32)(sum_m sim[b,m]*(x@K_m) + sim@b)
// Block tile 128x128, 4 waves of 64x64, grid (128 rowtiles, 4 modesplits).
// Double-buffered LDS staging of K_m (1 barrier/mode).  A-fragments built
// from x fp32 directly (in-register bf16 cvt).  Plain-store epilogue into
// per-split partials; the LAST split block to finish a rowtile (atomic
// counter, device-scope fences) reduces the 4 partials into out.
// ---------------------------------------------------------------------------
__global__ __launch_bounds__(256, 2) void gemm_poly(
    const float* __restrict__ x, const unsigned short* __restrict__ kb16,
    const unsigned short* __restrict__ bb16, const float* __restrict__ sim,
    float* __restrict__ partial, int* __restrict__ cnt,
    float* __restrict__ out) {
  __shared__ alignas(16) unsigned short bsh[2][16 * UDIM * 8];  // 2 x 32KB
  __shared__ alignas(16) float simT[8][128];                    // [mode_local][row]
  __shared__ int sOld;

  const int t = threadIdx.x;
  const int lane = t & 63, w = t >> 6;
  const int q = lane >> 4, l16 = lane & 15;
  const int wrow = (w >> 1) * 64, wcol = (w & 1) * 64;
  const long bm = (long)blockIdx.x * 128;
  const int split = blockIdx.y;  // modes [split*8, split*8+8)

  {  // stage sim (own 8 modes, 128 rows) transposed into LDS
    int rrow = t >> 1, mg = (t & 1) * 4;
    const float4 v = *(const float4*)(sim + (bm + rrow) * MODES + split * 8 + mg);
    simT[mg + 0][rrow] = v.x; simT[mg + 1][rrow] = v.y;
    simT[mg + 2][rrow] = v.z; simT[mg + 3][rrow] = v.w;
  }

  // A fragments from x fp32, cvt in-register: A[row=wrow+rt*16+l16][k=ks*32+q*8+j]
  bf16x8 aF[4][4];
  #pragma unroll
  for (int rt = 0; rt < 4; ++rt)
    #pragma unroll
    for (int ks = 0; ks < 4; ++ks) {
      const float* xp = x + (bm + wrow + rt * 16 + l16) * DDIM + ks * 32 + q * 8;
      const float4 lo = *(const float4*)xp;
      const float4 hi = *(const float4*)(xp + 4);
      bf16x8 f;
      f[0] = (short)f2bf(lo.x); f[1] = (short)f2bf(lo.y);
      f[2] = (short)f2bf(lo.z); f[3] = (short)f2bf(lo.w);
      f[4] = (short)f2bf(hi.x); f[5] = (short)f2bf(hi.y);
      f[6] = (short)f2bf(hi.z); f[7] = (short)f2bf(hi.w);
      aF[rt][ks] = f;
    }

  const unsigned short* kbase = kb16 + (long)(split * 8) * (16 * UDIM * 8);
  #pragma unroll
  for (int i = 0; i < 8; ++i) {  // stage mode 0 into buffer 0
    int off = (t + i * 256) * 8;
    gld_lds16(kbase + off, &bsh[0][off]);
  }

  f32x4 acc[4][4] = {};  // [rt][ct]

  for (int mi = 0; mi < 8; ++mi) {
    __syncthreads();  // drains vmcnt: bsh[mi&1] staged; prev-iter reads done
    if (mi < 7) {     // prefetch next mode into the other buffer
      const unsigned short* src = kbase + (long)(mi + 1) * (16 * UDIM * 8);
      unsigned short* dst = bsh[(mi + 1) & 1];
      #pragma unroll
      for (int i = 0; i < 8; ++i) {
        int off = (t + i * 256) * 8;
        gld_lds16(src + off, dst + off);
      }
    }

    const unsigned short* bs = bsh[mi & 1];
    bf16x8 bF[4][4];  // [ks][ct], contiguous 16B each, conflict-free b128
    #pragma unroll
    for (int ks = 0; ks < 4; ++ks)
      #pragma unroll
      for (int ct = 0; ct < 4; ++ct)
        bF[ks][ct] = *(const bf16x8*)&bs[(((ks * 4 + q) * UDIM) + wcol + ct * 16 + l16) * 8];

    #pragma unroll
    for (int rt = 0; rt < 4; ++rt) {
      f32x4 tmp[4] = {};
      #pragma unroll
      for (int ks = 0; ks < 4; ++ks)
        #pragma unroll
        for (int ct = 0; ct < 4; ++ct)
          tmp[ct] = __builtin_amdgcn_mfma_f32_16x16x32_bf16(aF[rt][ks], bF[ks][ct], tmp[ct], 0, 0, 0);
      const f32x4 s = *(const f32x4*)&simT[mi][wrow + rt * 16 + q * 4];
      #pragma unroll
      for (int ct = 0; ct < 4; ++ct)
        acc[rt][ct] += s * tmp[ct];
    }
  }

  // bias term: one K=32 MFMA round (A = sim bf16, B = biases). split 0 only.
  if (split == 0) {
    bf16x8 sF[4];
    #pragma unroll
    for (int rt = 0; rt < 4; ++rt) {
      const float* sp = sim + (bm + wrow + rt * 16 + l16) * MODES + q * 8;
      bf16x8 f;
      #pragma unroll
      for (int j = 0; j < 8; ++j) f[j] = (short)f2bf(sp[j]);
      sF[rt] = f;
    }
    #pragma unroll
    for (int ct = 0; ct < 4; ++ct) {
      bf16x8 bb = *(const bf16x8*)(bb16 + (long)(q * UDIM + wcol + ct * 16 + l16) * 8);
      #pragma unroll
      for (int rt = 0; rt < 4; ++rt)
        acc[rt][ct] = __builtin_amdgcn_mfma_f32_16x16x32_bf16(sF[rt], bb, acc[rt][ct], 0, 0, 0);
    }
  }

  // epilogue: plain stores to this split's private partial buffer
  const long S = (long)BATCH * UDIM;
  float* part = partial + (long)split * S;
  #pragma unroll
  for (int rt = 0; rt < 4; ++rt)
    #pragma unroll
    for (int ct = 0; ct < 4; ++ct) {
      long row = bm + wrow + rt * 16 + q * 4;
      int col = wcol + ct * 16 + l16;
      #pragma unroll
      for (int r = 0; r < 4; ++r)
        part[(row + r) * UDIM + col] = acc[rt][ct][r];
    }

  // fused reduce: last-arriving split for this rowtile sums the 4 partials
  __threadfence();  // release: partial stores visible device-wide
  if (t == 0) sOld = atomicAdd(&cnt[blockIdx.x], 1);
  __syncthreads();
  if (sOld == 3) {
    __threadfence();  // acquire: see all other splits' stores
    const f32x4* p0 = (const f32x4*)partial;
    const f32x4* p1 = (const f32x4*)(partial + S);
    const f32x4* p2 = (const f32x4*)(partial + 2 * S);
    const f32x4* p3 = (const f32x4*)(partial + 3 * S);
    f32x4* o4 = (f32x4*)out;
    const long base = bm * UDIM / 4;  // 4096 float4 per rowtile
    #pragma unroll
    for (int i = 0; i < 16; ++i) {
      long idx = base + i * 256 + t;
      o4[idx] = (p0[idx] + p1[idx] + p2[idx] + p3[idx]) * (1.0f / MODES);
    }
  }
}

extern "C" void kernel_launch(void* const* d_in, const int* in_sizes, int n_in,
                              void* d_out, int out_size, void* d_ws, size_t ws_size,
                              hipStream_t stream) {
  const float* key      = (const float*)d_in[0];
  const float* x        = (const float*)d_in[1];
  const float* sens     = (const float*)d_in[2];
  const float* keys_map = (const float*)d_in[3];
  const float* kernels  = (const float*)d_in[4];
  const float* biases   = (const float*)d_in[5];
  float* out = (float*)d_out;

  char* ws = (char*)d_ws;
  float*          sim  = (float*)ws;                            // 2 MB
  unsigned short* kb16 = (unsigned short*)(ws + (2u << 20));    // 1 MB
  unsigned short* bb16 = (unsigned short*)(ws + (3u << 20));    // 8 KB
  int*            cnt  = (int*)(ws + (3u << 20) + (512u << 10));// 512 B
  float*          part = (float*)(ws + (4u << 20));             // 4 x 8 MB

  prep_all<<<BATCH / 32 + 259, 256, 0, stream>>>(
      key, sens, keys_map, kernels, biases, sim, kb16, bb16, cnt);
  gemm_poly<<<dim3(BATCH / 128, 4), 256, 0, stream>>>(
      x, kb16, bb16, sim, part, cnt, out);
}

// Round 7
// 111.241 us; speedup vs baseline: 1.7185x; 1.7185x over previous
//
#include <hip/hip_runtime.h>

// Problem constants
#define BATCH 16384
#define KEYD  64
#define DDIM  128
#define UDIM  128
#define MODES 32

typedef __attribute__((ext_vector_type(8))) short bf16x8;   // 8 bf16 in 4 VGPRs
typedef __attribute__((ext_vector_type(4))) float f32x4;

__device__ __forceinline__ unsigned short f2bf(float f) {
  unsigned u = __float_as_uint(f);
  unsigned r = (u + 0x7FFFu + ((u >> 16) & 1u)) >> 16;  // RNE bf16
  return (unsigned short)r;
}

__device__ __forceinline__ void gld_lds16(const void* g, void* l) {
  __builtin_amdgcn_global_load_lds(
      (const __attribute__((address_space(1))) unsigned int*)g,
      (__attribute__((address_space(3))) unsigned int*)l, 16, 0, 0);
}

// ---------------------------------------------------------------------------
// Fused prep (one dispatch) — R4-proven:
//  blocks [0,512):   sim softmax (32 rows/block) + x->bf16 cast.
//  blocks [512,770): cast kernels+biases to bf16 in MFMA-B fragment layout
//    kb16[m][kblk][u][j] = kernels[m][kblk*8+j][u] -> every B-fragment is a
//    contiguous 16B chunk.
// ---------------------------------------------------------------------------
__global__ __launch_bounds__(256) void prep_all(
    const float* __restrict__ key, const float* __restrict__ x,
    const float* __restrict__ sens, const float* __restrict__ keys_map,
    const float* __restrict__ kernels, const float* __restrict__ biases,
    float* __restrict__ sim, unsigned short* __restrict__ x16,
    unsigned short* __restrict__ kb16, unsigned short* __restrict__ bb16) {
  const int t = threadIdx.x;
  const int bid = blockIdx.x;

  if (bid < BATCH / 32) {
    __shared__ float kr[32][KEYD];  // 32 key rows, 8KB
    *(float4*)(&kr[0][0] + t * 4) =
        *(const float4*)(key + (long)bid * 32 * KEYD + t * 4);
    *(float4*)(&kr[0][0] + 1024 + t * 4) =
        *(const float4*)(key + (long)bid * 32 * KEYD + 1024 + t * 4);

    const int lane = t & 63, wave = t >> 6;
    const int m = lane & 31, h = lane >> 5;
    float kreg[32];  // this lane's half of mode m's key row
    {
      const float* kmp = keys_map + m * KEYD + h * 32;
      #pragma unroll
      for (int j = 0; j < 32; j += 4) {
        const float4 v = *(const float4*)(kmp + j);
        kreg[j] = v.x; kreg[j + 1] = v.y; kreg[j + 2] = v.z; kreg[j + 3] = v.w;
      }
    }
    const float sv = sens[m];
    __syncthreads();

    #pragma unroll
    for (int rr = 0; rr < 8; ++rr) {
      const int rl = wave * 8 + rr;
      const long row = (long)bid * 32 + rl;

      float d2h = 0.f;
      #pragma unroll
      for (int j = 0; j < 32; j += 2) {
        const float2 kv = *(const float2*)(&kr[rl][h * 32 + j]);
        float a = kv.x - kreg[j], b = kv.y - kreg[j + 1];
        d2h += a * a + b * b;
      }
      float d2 = d2h + __shfl_xor(d2h, 32, 64);
      float logit = sv / (sqrtf(d2) + 1.0f);
      float mx = logit;
      #pragma unroll
      for (int off = 16; off > 0; off >>= 1) mx = fmaxf(mx, __shfl_xor(mx, off, 64));
      float e = __expf(logit - mx);
      float s = e;
      #pragma unroll
      for (int off = 16; off > 0; off >>= 1) s += __shfl_xor(s, off, 64);
      if (h == 0) sim[row * MODES + m] = e / s;

      const float2 xv = *(const float2*)(x + row * DDIM + lane * 2);
      ushort2 o; o.x = f2bf(xv.x); o.y = f2bf(xv.y);
      *(ushort2*)(x16 + row * DDIM + lane * 2) = o;
    }
  } else {
    int tt = (bid - BATCH / 32) * 256 + t;
    if (tt < MODES * 16 * UDIM) {  // 65536 chunks of 8
      int u = tt & 127, kb = (tt >> 7) & 15, m = tt >> 11;
      const float* src = kernels + (long)((m * 16 + kb) * 8) * UDIM + u;
      ushort4 lo, hi;
      lo.x = f2bf(src[0 * UDIM]); lo.y = f2bf(src[1 * UDIM]);
      lo.z = f2bf(src[2 * UDIM]); lo.w = f2bf(src[3 * UDIM]);
      hi.x = f2bf(src[4 * UDIM]); hi.y = f2bf(src[5 * UDIM]);
      hi.z = f2bf(src[6 * UDIM]); hi.w = f2bf(src[7 * UDIM]);
      *(ushort4*)(kb16 + (long)tt * 8) = lo;
      *(ushort4*)(kb16 + (long)tt * 8 + 4) = hi;
    } else {  // 512 bias chunks
      int tb = tt - MODES * 16 * UDIM;
      int u = tb & 127, kb = tb >> 7;
      const float* src = biases + kb * 8 * UDIM + u;
      ushort4 lo, hi;
      lo.x = f2bf(src[0 * UDIM]); lo.y = f2bf(src[1 * UDIM]);
      lo.z = f2bf(src[2 * UDIM]); lo.w = f2bf(src[3 * UDIM]);
      hi.x = f2bf(src[4 * UDIM]); hi.y = f2bf(src[5 * UDIM]);
      hi.z = f2bf(src[6 * UDIM]); hi.w = f2bf(src[7 * UDIM]);
      *(ushort4*)(bb16 + (long)tb * 8) = lo;
      *(ushort4*)(bb16 + (long)tb * 8 + 4) = hi;
    }
  }
}

// ---------------------------------------------------------------------------
// GEMM, no mode-split: each block computes ALL 32 modes for its
// 128-row x 64-col tile and writes out directly (/32, bias folded in).
// Grid (128 rowtiles, 2 colhalves) = 256 blocks (1/CU).  4 waves stacked in
// rows (wave 32x64).  Double-buffered 16KB LDS staging, 1 barrier/mode; the
// prefetch for mode mi+1 is issued right after the barrier opening mi, so
// its drain overlaps the whole compute phase.  No partials / atomics /
// fences / reduce dispatch.
// ---------------------------------------------------------------------------
__global__ __launch_bounds__(256) void gemm_poly(
    const unsigned short* __restrict__ x16, const unsigned short* __restrict__ kb16,
    const unsigned short* __restrict__ bb16, const float* __restrict__ sim,
    float* __restrict__ out) {
  __shared__ alignas(16) unsigned short bsh[2][16 * 64 * 8];  // 2 x 16KB
  __shared__ alignas(16) float simT[MODES][128];              // [mode][row] 16KB

  const int t = threadIdx.x;
  const int lane = t & 63, w = t >> 6;
  const int q = lane >> 4, l16 = lane & 15;
  const int wrow = w * 32;                 // wave's rows in block tile
  const long bm = (long)blockIdx.x * 128;
  const int c0 = blockIdx.y * 64;          // column half

  {  // stage sim (all 32 modes, 128 rows) transposed: 2 threads/row
    int rrow = t >> 1, mg = (t & 1) * 16;
    const float* sp = sim + (bm + rrow) * MODES + mg;
    #pragma unroll
    for (int g = 0; g < 4; ++g) {
      const float4 v = *(const float4*)(sp + g * 4);
      simT[mg + g * 4 + 0][rrow] = v.x; simT[mg + g * 4 + 1][rrow] = v.y;
      simT[mg + g * 4 + 2][rrow] = v.z; simT[mg + g * 4 + 3][rrow] = v.w;
    }
  }

  // A fragments (x, bf16): A[row = wrow+rt*16+l16][k = ks*32+q*8+j]
  bf16x8 aF[2][4];
  #pragma unroll
  for (int rt = 0; rt < 2; ++rt)
    #pragma unroll
    for (int ks = 0; ks < 4; ++ks)
      aF[rt][ks] = *(const bf16x8*)(x16 + (bm + wrow + rt * 16 + l16) * DDIM + ks * 32 + q * 8);

  // stage mode 0's col-half slice into buffer 0: 16 chunks of 1KB
  #pragma unroll
  for (int i = 0; i < 4; ++i) {
    int e = (t + i * 256) * 8;            // LDS elem offset (16B per lane)
    int kblk = e >> 9, within = e & 511;  // 512 elems (64 cols x 8) per kblk
    gld_lds16(kb16 + c0 * 8 + (long)kblk * (UDIM * 8) + within,
              (unsigned short*)&bsh[0][0] + e);
  }

  f32x4 acc[2][4] = {};  // [rt][ct]

  for (int m = 0; m < MODES; ++m) {
    __syncthreads();  // drains vmcnt: bsh[m&1] staged; prev-iter reads done
    if (m < MODES - 1) {  // prefetch next mode into the other buffer
      const unsigned short* msrc = kb16 + (long)(m + 1) * (16 * UDIM * 8) + c0 * 8;
      unsigned short* dst = &bsh[(m + 1) & 1][0];
      #pragma unroll
      for (int i = 0; i < 4; ++i) {
        int e = (t + i * 256) * 8;
        int kblk = e >> 9, within = e & 511;
        gld_lds16(msrc + (long)kblk * (UDIM * 8) + within, dst + e);
      }
    }

    const unsigned short* bs = &bsh[m & 1][0];
    bf16x8 bF[4][4];  // [ks][ct]: contiguous 16B, 2-way-free bank pattern
    #pragma unroll
    for (int ks = 0; ks < 4; ++ks)
      #pragma unroll
      for (int ct = 0; ct < 4; ++ct)
        bF[ks][ct] = *(const bf16x8*)&bs[(((ks * 4 + q) * 64) + ct * 16 + l16) * 8];

    #pragma unroll
    for (int rt = 0; rt < 2; ++rt) {
      f32x4 tmp[4] = {};
      #pragma unroll
      for (int ks = 0; ks < 4; ++ks)
        #pragma unroll
        for (int ct = 0; ct < 4; ++ct)
          tmp[ct] = __builtin_amdgcn_mfma_f32_16x16x32_bf16(aF[rt][ks], bF[ks][ct], tmp[ct], 0, 0, 0);
      const f32x4 s = *(const f32x4*)&simT[m][wrow + rt * 16 + q * 4];
      #pragma unroll
      for (int ct = 0; ct < 4; ++ct)
        acc[rt][ct] += s * tmp[ct];
    }
  }

  // bias term: one K=32 MFMA round (A = sim bf16 over all 32 modes, B = biases)
  {
    bf16x8 sF[2];
    #pragma unroll
    for (int rt = 0; rt < 2; ++rt) {
      const float* sp = sim + (bm + wrow + rt * 16 + l16) * MODES + q * 8;
      bf16x8 f;
      #pragma unroll
      for (int j = 0; j < 8; ++j) f[j] = (short)f2bf(sp[j]);
      sF[rt] = f;
    }
    #pragma unroll
    for (int ct = 0; ct < 4; ++ct) {
      bf16x8 bb = *(const bf16x8*)(bb16 + (long)(q * UDIM + c0 + ct * 16 + l16) * 8);
      #pragma unroll
      for (int rt = 0; rt < 2; ++rt)
        acc[rt][ct] = __builtin_amdgcn_mfma_f32_16x16x32_bf16(sF[rt], bb, acc[rt][ct], 0, 0, 0);
    }
  }

  // epilogue: direct stores to out, scaled by 1/MODES
  #pragma unroll
  for (int rt = 0; rt < 2; ++rt)
    #pragma unroll
    for (int ct = 0; ct < 4; ++ct) {
      long row = bm + wrow + rt * 16 + q * 4;
      int col = c0 + ct * 16 + l16;
      #pragma unroll
      for (int r = 0; r < 4; ++r)
        out[(row + r) * UDIM + col] = acc[rt][ct][r] * (1.0f / MODES);
    }
}

extern "C" void kernel_launch(void* const* d_in, const int* in_sizes, int n_in,
                              void* d_out, int out_size, void* d_ws, size_t ws_size,
                              hipStream_t stream) {
  const float* key      = (const float*)d_in[0];
  const float* x        = (const float*)d_in[1];
  const float* sens     = (const float*)d_in[2];
  const float* keys_map = (const float*)d_in[3];
  const float* kernels  = (const float*)d_in[4];
  const float* biases   = (const float*)d_in[5];
  float* out = (float*)d_out;

  char* ws = (char*)d_ws;
  float*          sim  = (float*)ws;                          // 2 MB
  unsigned short* x16  = (unsigned short*)(ws + (2u << 20));  // 4 MB
  unsigned short* kb16 = (unsigned short*)(ws + (6u << 20));  // 1 MB
  unsigned short* bb16 = (unsigned short*)(ws + (7u << 20));  // 8 KB

  prep_all<<<BATCH / 32 + 258, 256, 0, stream>>>(
      key, x, sens, keys_map, kernels, biases, sim, x16, kb16, bb16);
  gemm_poly<<<dim3(BATCH / 128, 2), 256, 0, stream>>>(x16, kb16, bb16, sim, out);
}